// Round 12
// baseline (232.435 us; speedup 1.0000x reference)
//
#include <hip/hip_runtime.h>

typedef short v8s __attribute__((ext_vector_type(8)));
typedef float v4f __attribute__((ext_vector_type(4)));

#define N_  16
#define CI_ 32
#define CO_ 64
#define DI  16
#define HI  32
#define WI  32
#define NEGINF (-__builtin_inff())

__device__ __forceinline__ unsigned short f2bf(float f) {
    unsigned int u = __float_as_uint(f);
    unsigned int r = (u + 0x7FFFu + ((u >> 16) & 1u)) >> 16;
    return (unsigned short)r;
}

// Per-class base offsets in halves: 2048 * cumsum(taps).
__constant__ int O64c[9] = {0, 55296, 92160, 129024, 153600, 190464, 215040, 239616, 256000};

// w -> wt in MFMA-native wave order (R9-proven):
//   wt[O64[r] + ((tap*4+nt)*64 + q*16 + l)*8 + j] = bf16(w[ci][co][kd][kh][kw])
//   with co = nt*16+l, ci = q*8+j  ==> every B load is a contiguous 1KB/wave.
// x-prep is GONE: R3..R11 carried an xp intermediate whose only benefit was
// one-time staging VALU (~1% of block life); its serialized launch+pass cost
// ~60-73us every round.
__global__ void wprep(const float* __restrict__ w, unsigned short* __restrict__ wt) {
    int u = blockIdx.x * 256 + threadIdx.x;   // grid 1000 * 256 = 256000 exactly
    int r = 0;
    #pragma unroll
    for (int i = 1; i < 8; ++i) r += (u >= O64c[i]);
    const int rd = r >> 2, rh = (r >> 1) & 1, rw = r & 1;
    const int nh = rh ? 2 : 3, nw = rw ? 2 : 3;
    int t2 = u - O64c[r];
    int j   = t2 & 7;
    int l   = (t2 >> 3) & 15;
    int q   = (t2 >> 7) & 3;
    int nt  = (t2 >> 9) & 3;
    int tap = t2 >> 11;
    int co = nt * 16 + l;
    int ci = q * 8 + j;
    int jw = tap % nw;
    int jh = (tap / nw) % nh;
    int jd = tap / (nw * nh);
    int kd = rd + 2 * jd, kh = rh + 2 * jh, kw = rw + 2 * jw;
    wt[u] = f2bf(w[(ci * CO_ + co) * 125 + kd * 25 + kh * 5 + kw]);
}

// Per-class GEMM body with RUNTIME parity (R11-proven). Exactly ONE inlined
// instance per kernel (>=4 inlined bodies spill: R7/R9/R10 WRITE 150-494MB;
// rolled single does not: R3/R6/R11 WRITE 75KB). par is block-uniform.
__device__ __forceinline__ void run_class_rt(
        const unsigned short* __restrict__ xs,   // LDS patch
        int laneAB,                              // byte addr: q*7200 + (l+2)*16 + 3456
        const unsigned short* __restrict__ wcls, // wt + O64[r] + lane*8 (swizzled)
        const int taps, const int nw, const int nh, const bool par,
        unsigned Bm, bool isQ3, float (&pmax)[4][2])
{
    const int R0 = par ? 288 : 0;
    const int R1 = par ? 1440 : 576;
    const int R2 = par ? 2016 : 1728;
    const int R3_ = par ? 3168 : 2880;

    const char* xb = (const char*)xs;

    v4f acc[5][4];
    #pragma unroll
    for (int t = 0; t < 5; ++t)
        #pragma unroll
        for (int nt = 0; nt < 4; ++nt)
            acc[t][nt] = (v4f){0.f, 0.f, 0.f, 0.f};

    v8s B0[4], B1[4];
    #pragma unroll
    for (int nt = 0; nt < 4; ++nt) B0[nt] = *(const v8s*)(wcls + nt * 512);

    int aoff = 0, jw = 0, jh = 0;
    auto adv = [&]() {
        aoff += 16; ++jw;
        if (jw == nw) { jw = 0; aoff += 288 - 16 * nw; ++jh;
            if (jh == nh) { jh = 0; aoff += 1440 - 288 * nh; } }
    };
    auto comp = [&](const v8s (&B)[4]) {
        const int va = laneAB - aoff;
        v8s a0 = *(const v8s*)(xb + va + R0);
        v8s a1 = *(const v8s*)(xb + va + R1);
        v8s a2 = *(const v8s*)(xb + va + R2);
        v8s a3 = *(const v8s*)(xb + va + R3_);
        #pragma unroll
        for (int nt = 0; nt < 4; ++nt) {
            acc[0][nt] = __builtin_amdgcn_mfma_f32_16x16x32_bf16(a0, B[nt], acc[0][nt], 0, 0, 0);
            acc[1][nt] = __builtin_amdgcn_mfma_f32_16x16x32_bf16(a1, B[nt], acc[1][nt], 0, 0, 0);
            acc[2][nt] = __builtin_amdgcn_mfma_f32_16x16x32_bf16(a2, B[nt], acc[2][nt], 0, 0, 0);
            acc[3][nt] = __builtin_amdgcn_mfma_f32_16x16x32_bf16(a3, B[nt], acc[3][nt], 0, 0, 0);
        }
        if (!par) {                       // block-uniform branch
            v8s a4 = *(const v8s*)(xb + va + 3456);
            #pragma unroll
            for (int nt = 0; nt < 4; ++nt)
                acc[4][nt] = __builtin_amdgcn_mfma_f32_16x16x32_bf16(a4, B[nt], acc[4][nt], 0, 0, 0);
        }
    };

    int s = 0;
    while (s + 2 <= taps) {
        #pragma unroll
        for (int nt = 0; nt < 4; ++nt)
            B1[nt] = *(const v8s*)(wcls + ((s + 1) * 4 + nt) * 512);
        comp(B0); adv();
        if (s + 2 < taps) {
            #pragma unroll
            for (int nt = 0; nt < 4; ++nt)
                B0[nt] = *(const v8s*)(wcls + ((s + 2) * 4 + nt) * 512);
        }
        comp(B1); adv();
        s += 2;
    }
    if (s < taps) comp(B0);

    // fold: max over rows (runtime T via uniform guard), then slot dispatch
    #pragma unroll
    for (int nt = 0; nt < 4; ++nt) {
        #pragma unroll
        for (int reg = 0; reg < 4; ++reg) {
            float v = acc[0][nt][reg];
            v = fmaxf(v, acc[1][nt][reg]);
            v = fmaxf(v, acc[2][nt][reg]);
            v = fmaxf(v, acc[3][nt][reg]);
            if (!par) v = fmaxf(v, acc[4][nt][reg]);
            if (reg == 3) v = isQ3 ? NEGINF : v;   // skip m==15
            const bool bB = (Bm >> reg) & 1u;
            pmax[nt][0] = fmaxf(pmax[nt][0], bB ? NEGINF : v);
            pmax[nt][1] = fmaxf(pmax[nt][1], bB ? v : NEGINF);
        }
    }
}

// 256 threads = 4 waves = 4 class-pairs; each wave runs 4 rolled passes
// (parity x class) through ONE run_class_rt body (R11 structure, 117us,
// MfmaUtil 44.7%, no spill). Staging is now INLINE from fp32 x (R2-proven
// math): one-time ~700 VALU-cyc/thread vs ~70K-cyc block life; kills the
// serialized x-prep pass (~60-73us window every round since R3).
__global__ __launch_bounds__(256, 3)
void fused_main(const float* __restrict__ x,
                const unsigned short* __restrict__ wt,
                const float* __restrict__ bias, float* __restrict__ out) {
    __shared__ __align__(16) char smem[28800];
    unsigned short* xs = (unsigned short*)smem;   // [g4][id'5][ih'5][iw'18][c8]
    float* P = (float*)smem;                      // [wave4][q4][l16][9] (8 used + pad)
    float* Y = (float*)(smem + 9472);             // [co64][wjl5]

    const int b = blockIdx.x;
    const int whalf = b & 1;
    const int hj = (b >> 1) % 10;
    const int dj = (b / 20) % 5;
    const int n  = b / 100;

    const int lane = threadIdx.x & 63;
    const int wv   = threadIdx.x >> 6;

    // ---- inline staging from raw fp32 x (R2-proven; bounds: id<=15,
    // ih<=30, iw<=31 never exceed; zero only at negative edges) ----
    {
        const int id0 = 3 * dj - 1, ih0 = 3 * hj - 1, iwb = 15 * whalf - 1;
        const float* xn = x + (size_t)n * (CI_ * DI * HI * WI);
        for (int e = threadIdx.x; e < 14400; e += 256) {
            int ci   = e / 450;
            int rem  = e - ci * 450;
            int idp  = rem / 90;
            int rem2 = rem - idp * 90;
            int ihp  = rem2 / 18;
            int iwp  = rem2 - ihp * 18;
            int id = id0 + idp, ih = ih0 + ihp, iw = iwb + iwp;
            float v = 0.f;
            if (id >= 0 && ih >= 0 && iw >= 0)
                v = xn[((ci * DI + id) * HI + ih) * WI + iw];
            xs[(ci >> 3) * 3600 + idp * 720 + ihp * 144 + iwp * 8 + (ci & 7)] = f2bf(v);
        }
    }
    __syncthreads();

    const int l = lane & 15, q = lane >> 4;
    const int laneAB = q * 7200 + (l + 2) * 16 + 3456;  // bytes

    static constexpr int PT[4][2] = {{0, 7}, {1, 3}, {2, 5}, {4, 6}};
    static constexpr int tapsT[8] = {27, 18, 18, 12, 18, 12, 12, 8};
    static constexpr int O64[8]   = {0, 55296, 92160, 129024, 153600, 190464, 215040, 239616};
    static constexpr int nwT[8]   = {3, 2, 3, 2, 3, 2, 3, 2};
    static constexpr int nhT[8]   = {3, 3, 2, 2, 3, 3, 2, 2};

    float pmax[4][2];
    #pragma unroll
    for (int nt = 0; nt < 4; ++nt) { pmax[nt][0] = NEGINF; pmax[nt][1] = NEGINF; }

    const unsigned Bm = (0x0EC8u >> (q << 2)) & 0xFu;
    const bool isQ3 = (q == 3);

    // 4 rolled passes: it = parity*2 + class. ONE run_class_rt inline site.
    #pragma unroll 1
    for (int it = 0; it < 4; ++it) {
        const bool par = (it >> 1) != 0;
        const int  r   = PT[wv][it & 1];
        run_class_rt(xs, laneAB, wt + O64[r] + lane * 8,
                     tapsT[r], nwT[r], nhT[r], par, Bm, isQ3, pmax);
    }

    // ---- cross-wave reduction (P overlays xs; barrier first) ----
    __syncthreads();
    {
        int base = ((wv * 4 + q) * 16 + l) * 9;
        #pragma unroll
        for (int nt = 0; nt < 4; ++nt) {
            P[base + nt * 2 + 0] = pmax[nt][0];
            P[base + nt * 2 + 1] = pmax[nt][1];
        }
    }
    __syncthreads();

    static constexpr int wjAt[4] = {0, 1, 2, 4};
    static constexpr int wjBt[4] = {1, 2, 3, 5};
    for (int oi = threadIdx.x; oi < 320; oi += 256) {
        int co = oi / 5;
        int wjl = oi - co * 5;
        int lc = co & 15, ntc = co >> 4;
        float v = NEGINF;
        #pragma unroll
        for (int w = 0; w < 4; ++w) {
            #pragma unroll
            for (int qq = 0; qq < 4; ++qq) {
                const float* pp = &P[((w * 4 + qq) * 16 + lc) * 9 + ntc * 2];
                if (wjAt[qq] == wjl) v = fmaxf(v, pp[0]);
                if (wjBt[qq] == wjl) v = fmaxf(v, pp[1]);
            }
        }
        Y[co * 5 + wjl] = v + bias[co];
    }
    __syncthreads();

    if (threadIdx.x < 5) {
        float s = 0.f;
        #pragma unroll
        for (int co = 0; co < 64; ++co) s += Y[co * 5 + threadIdx.x];
        out[((n * 5 + dj) * 10 + hj) * 10 + whalf * 5 + threadIdx.x] = s;
    }
}

extern "C" void kernel_launch(void* const* d_in, const int* in_sizes, int n_in,
                              void* d_out, int out_size, void* d_ws, size_t ws_size,
                              hipStream_t stream) {
    const float* x    = (const float*)d_in[0];
    const float* w    = (const float*)d_in[1];
    const float* bias = (const float*)d_in[2];
    float*       out  = (float*)d_out;
    unsigned short* wt = (unsigned short*)d_ws;   // 512000 B

    wprep<<<dim3(1000), 256, 0, stream>>>(w, wt);
    fused_main<<<dim3(1600), 256, 0, stream>>>(x, wt, bias, out);
}

// Round 13
// 188.537 us; speedup vs baseline: 1.2328x; 1.2328x over previous
//
#include <hip/hip_runtime.h>

typedef short v8s __attribute__((ext_vector_type(8)));
typedef float v4f __attribute__((ext_vector_type(4)));

#define N_  16
#define CI_ 32
#define CO_ 64
#define DI  16
#define HI  32
#define WI  32
#define NEGINF (-__builtin_inff())

__device__ __forceinline__ unsigned short f2bf(float f) {
    unsigned int u = __float_as_uint(f);
    unsigned int r = (u + 0x7FFFu + ((u >> 16) & 1u)) >> 16;
    return (unsigned short)r;
}

// async 16B global->LDS (LDS dst = wave-uniform base + lane*16)
__device__ __forceinline__ void gld16(const void* g, void* l) {
    __builtin_amdgcn_global_load_lds(
        (const __attribute__((address_space(1))) void*)g,
        (__attribute__((address_space(3))) void*)l, 16, 0, 0);
}

// Per-class base offsets in halves: 2048 * cumsum(taps).
__constant__ int O64c[9] = {0, 55296, 92160, 129024, 153600, 190464, 215040, 239616, 256000};

// Fused prep (R9/R11-proven).
// Blocks [0,1088): coalesced x->bf16 transpose via LDS -> xp
//   [n][cg4][pd17][ph32][pw33][c8]; zero pad at pd==0||ph==0||pw==0.
// Blocks [1088,2088): w -> wt in MFMA-native wave order (1KB/wave B loads).
// NOTE (R12 measurement): the 2-dispatch window floor is ~57us regardless of
// prep size; xprep's marginal cost is only ~16us, while inlining staging into
// fused_main costs +58us (R12). Keep the xp pass.
__global__ void prep(const float* __restrict__ x, const float* __restrict__ w,
                     unsigned short* __restrict__ xp, unsigned short* __restrict__ wt,
                     int do_x) {
    if (blockIdx.x < 1088) {
        if (!do_x) return;
        __shared__ __align__(16) unsigned short tl[8192];   // [h32][w32][c8] bf16
        const int bi = blockIdx.x;
        const int pd = bi % 17;
        const int cg = (bi / 17) & 3;
        const int n  = bi / 68;
        if (pd > 0) {
            const int c = threadIdx.x >> 5;       // 0..7
            const int ww = threadIdx.x & 31;      // 0..31
            const float* xc = x + (((size_t)(n * 32 + cg * 8 + c) * 16 + (pd - 1)) * 32) * 32;
            #pragma unroll
            for (int h = 0; h < 32; ++h)
                tl[(h * 32 + ww) * 8 + c] = f2bf(xc[h * 32 + ww]);
        }
        __syncthreads();
        unsigned short* xpo = xp + (size_t)bi * 8448;   // 32*33*8
        for (int o = threadIdx.x; o < 1056; o += 256) {
            int ph = o / 33, pw = o - ph * 33;
            v8s v;
            if (pd == 0 || ph == 0 || pw == 0) v = (v8s){0, 0, 0, 0, 0, 0, 0, 0};
            else v = *(const v8s*)&tl[((ph - 1) * 32 + pw - 1) * 8];
            *(v8s*)(xpo + o * 8) = v;
        }
    } else {
        int u = (blockIdx.x - 1088) * 256 + threadIdx.x;
        if (u >= 256000) return;
        int r = 0;
        #pragma unroll
        for (int i = 1; i < 8; ++i) r += (u >= O64c[i]);
        const int rd = r >> 2, rh = (r >> 1) & 1, rw = r & 1;
        const int nh = rh ? 2 : 3, nw = rw ? 2 : 3;
        int t2 = u - O64c[r];
        int j   = t2 & 7;
        int l   = (t2 >> 3) & 15;
        int q   = (t2 >> 7) & 3;
        int nt  = (t2 >> 9) & 3;
        int tap = t2 >> 11;
        int co = nt * 16 + l;
        int ci = q * 8 + j;
        int jw = tap % nw;
        int jh = (tap / nw) % nh;
        int jd = tap / (nw * nh);
        int kd = rd + 2 * jd, kh = rh + 2 * jh, kw = rw + 2 * jw;
        wt[u] = f2bf(w[(ci * CO_ + co) * 125 + kd * 25 + kh * 5 + kw]);
    }
}

// Per-class GEMM body with RUNTIME parity (R11-proven). Exactly ONE inlined
// instance per kernel (>=4 inlined bodies spill: R7/R9/R10 WRITE 150-494MB;
// rolled single does not: R3/R6/R11 WRITE 75KB). par is block-uniform.
// Accumulator-lifetime wall (R4..R12): acc must live across the whole tap
// loop (pool-max only after full accumulation), so rows x nt per pass caps
// at 80 regs; total ~160/wave -> 3 waves/SIMD is the residency ceiling.
__device__ __forceinline__ void run_class_rt(
        const unsigned short* __restrict__ xs,   // LDS patch
        int laneAB,                              // byte addr: q*7200 + (l+2)*16 + 3456
        const unsigned short* __restrict__ wcls, // wt + O64[r] + lane*8 (swizzled)
        const int taps, const int nw, const int nh, const bool par,
        unsigned Bm, bool isQ3, float (&pmax)[4][2])
{
    const int R0 = par ? 288 : 0;
    const int R1 = par ? 1440 : 576;
    const int R2 = par ? 2016 : 1728;
    const int R3_ = par ? 3168 : 2880;

    const char* xb = (const char*)xs;

    v4f acc[5][4];
    #pragma unroll
    for (int t = 0; t < 5; ++t)
        #pragma unroll
        for (int nt = 0; nt < 4; ++nt)
            acc[t][nt] = (v4f){0.f, 0.f, 0.f, 0.f};

    v8s B0[4], B1[4];
    #pragma unroll
    for (int nt = 0; nt < 4; ++nt) B0[nt] = *(const v8s*)(wcls + nt * 512);

    int aoff = 0, jw = 0, jh = 0;
    auto adv = [&]() {
        aoff += 16; ++jw;
        if (jw == nw) { jw = 0; aoff += 288 - 16 * nw; ++jh;
            if (jh == nh) { jh = 0; aoff += 1440 - 288 * nh; } }
    };
    auto comp = [&](const v8s (&B)[4]) {
        const int va = laneAB - aoff;
        v8s a0 = *(const v8s*)(xb + va + R0);
        v8s a1 = *(const v8s*)(xb + va + R1);
        v8s a2 = *(const v8s*)(xb + va + R2);
        v8s a3 = *(const v8s*)(xb + va + R3_);
        #pragma unroll
        for (int nt = 0; nt < 4; ++nt) {
            acc[0][nt] = __builtin_amdgcn_mfma_f32_16x16x32_bf16(a0, B[nt], acc[0][nt], 0, 0, 0);
            acc[1][nt] = __builtin_amdgcn_mfma_f32_16x16x32_bf16(a1, B[nt], acc[1][nt], 0, 0, 0);
            acc[2][nt] = __builtin_amdgcn_mfma_f32_16x16x32_bf16(a2, B[nt], acc[2][nt], 0, 0, 0);
            acc[3][nt] = __builtin_amdgcn_mfma_f32_16x16x32_bf16(a3, B[nt], acc[3][nt], 0, 0, 0);
        }
        if (!par) {                       // block-uniform branch
            v8s a4 = *(const v8s*)(xb + va + 3456);
            #pragma unroll
            for (int nt = 0; nt < 4; ++nt)
                acc[4][nt] = __builtin_amdgcn_mfma_f32_16x16x32_bf16(a4, B[nt], acc[4][nt], 0, 0, 0);
        }
    };

    int s = 0;
    while (s + 2 <= taps) {
        #pragma unroll
        for (int nt = 0; nt < 4; ++nt)
            B1[nt] = *(const v8s*)(wcls + ((s + 1) * 4 + nt) * 512);
        comp(B0); adv();
        if (s + 2 < taps) {
            #pragma unroll
            for (int nt = 0; nt < 4; ++nt)
                B0[nt] = *(const v8s*)(wcls + ((s + 2) * 4 + nt) * 512);
        }
        comp(B1); adv();
        s += 2;
    }
    if (s < taps) comp(B0);

    // fold: max over rows (runtime T via uniform guard), then slot dispatch
    #pragma unroll
    for (int nt = 0; nt < 4; ++nt) {
        #pragma unroll
        for (int reg = 0; reg < 4; ++reg) {
            float v = acc[0][nt][reg];
            v = fmaxf(v, acc[1][nt][reg]);
            v = fmaxf(v, acc[2][nt][reg]);
            v = fmaxf(v, acc[3][nt][reg]);
            if (!par) v = fmaxf(v, acc[4][nt][reg]);
            if (reg == 3) v = isQ3 ? NEGINF : v;   // skip m==15
            const bool bB = (Bm >> reg) & 1u;
            pmax[nt][0] = fmaxf(pmax[nt][0], bB ? NEGINF : v);
            pmax[nt][1] = fmaxf(pmax[nt][1], bB ? v : NEGINF);
        }
    }
}

// R11 structure (117us, MfmaUtil 44.7%, no spill) + micro-opts:
//  - pass order {A,p0},{A,p1},{B,p0},{B,p1}: second parity re-reads the
//    identical B stream one pass later (L1/L2 temporal reuse).
//  - epilogue: wave-0 butterfly shuffle channel-sum instead of the serial
//    64-iteration loop on 5 threads.
template<bool PRE>
__global__ __launch_bounds__(256, 3)
void fused_main(const float* __restrict__ x, const unsigned short* __restrict__ xp,
                const unsigned short* __restrict__ wt,
                const float* __restrict__ bias, float* __restrict__ out) {
    __shared__ __align__(16) char smem[28800];
    unsigned short* xs = (unsigned short*)smem;   // [g4][id'5][ih'5][iw'18][c8]
    float* P = (float*)smem;                      // [wave4][q4][l16][9] (8 used + pad)
    float* Y = (float*)(smem + 9472);             // [co64][wjl5]

    const int b = blockIdx.x;
    const int whalf = b & 1;
    const int hj = (b >> 1) % 10;
    const int dj = (b / 20) % 5;
    const int n  = b / 100;

    const int lane = threadIdx.x & 63;
    const int wv   = threadIdx.x >> 6;

    if (PRE) {
        // DMA staging: 1800 chunks x 16B from pre-padded xp
        const int t = threadIdx.x;
        #pragma unroll
        for (int i = 0; i < 8; ++i) {
            int c = i * 256 + t;
            if (c < 1800) {
                int row = c / 18;
                int iwc = c - row * 18;
                int cg  = row / 25;
                int rr  = row - cg * 25;
                int idl = rr / 5;
                int ihl = rr - idl * 5;
                size_t goff = ((((size_t)((n * 4 + cg) * 17 + 3 * dj + idl)) * 32
                                + 3 * hj + ihl) * 33 + 15 * whalf + iwc) * 8;
                gld16(xp + goff, smem + i * 4096 + wv * 1024);
            }
        }
    } else {
        const int id0 = 3 * dj - 1, ih0 = 3 * hj - 1, iwb = 15 * whalf - 1;
        const float* xn = x + (size_t)n * (CI_ * DI * HI * WI);
        for (int e = threadIdx.x; e < 14400; e += 256) {
            int ci   = e / 450;
            int rem  = e - ci * 450;
            int idp  = rem / 90;
            int rem2 = rem - idp * 90;
            int ihp  = rem2 / 18;
            int iwp  = rem2 - ihp * 18;
            int id = id0 + idp, ih = ih0 + ihp, iw = iwb + iwp;
            float v = 0.f;
            if (id >= 0 && ih >= 0 && iw >= 0)
                v = xn[((ci * DI + id) * HI + ih) * WI + iw];
            xs[(ci >> 3) * 3600 + idp * 720 + ihp * 144 + iwp * 8 + (ci & 7)] = f2bf(v);
        }
    }
    __syncthreads();

    const int l = lane & 15, q = lane >> 4;
    const int laneAB = q * 7200 + (l + 2) * 16 + 3456;  // bytes

    static constexpr int PT[4][2] = {{0, 7}, {1, 3}, {2, 5}, {4, 6}};
    static constexpr int tapsT[8] = {27, 18, 18, 12, 18, 12, 12, 8};
    static constexpr int O64[8]   = {0, 55296, 92160, 129024, 153600, 190464, 215040, 239616};
    static constexpr int nwT[8]   = {3, 2, 3, 2, 3, 2, 3, 2};
    static constexpr int nhT[8]   = {3, 3, 2, 2, 3, 3, 2, 2};

    float pmax[4][2];
    #pragma unroll
    for (int nt = 0; nt < 4; ++nt) { pmax[nt][0] = NEGINF; pmax[nt][1] = NEGINF; }

    const unsigned Bm = (0x0EC8u >> (q << 2)) & 0xFu;
    const bool isQ3 = (q == 3);

    // 4 rolled passes: it = class*2 + parity (same-class passes adjacent for
    // B-stream temporal reuse). ONE run_class_rt inline site.
    #pragma unroll 1
    for (int it = 0; it < 4; ++it) {
        const bool par = (it & 1) != 0;
        const int  r   = PT[wv][it >> 1];
        run_class_rt(xs, laneAB, wt + O64[r] + lane * 8,
                     tapsT[r], nwT[r], nhT[r], par, Bm, isQ3, pmax);
    }

    // ---- cross-wave reduction (P overlays xs; barrier first) ----
    __syncthreads();
    {
        int base = ((wv * 4 + q) * 16 + l) * 9;
        #pragma unroll
        for (int nt = 0; nt < 4; ++nt) {
            P[base + nt * 2 + 0] = pmax[nt][0];
            P[base + nt * 2 + 1] = pmax[nt][1];
        }
    }
    __syncthreads();

    static constexpr int wjAt[4] = {0, 1, 2, 4};
    static constexpr int wjBt[4] = {1, 2, 3, 5};
    for (int oi = threadIdx.x; oi < 320; oi += 256) {
        int co = oi / 5;
        int wjl = oi - co * 5;
        int lc = co & 15, ntc = co >> 4;
        float v = NEGINF;
        #pragma unroll
        for (int w = 0; w < 4; ++w) {
            #pragma unroll
            for (int qq = 0; qq < 4; ++qq) {
                const float* pp = &P[((w * 4 + qq) * 16 + lc) * 9 + ntc * 2];
                if (wjAt[qq] == wjl) v = fmaxf(v, pp[0]);
                if (wjBt[qq] == wjl) v = fmaxf(v, pp[1]);
            }
        }
        Y[co * 5 + wjl] = v + bias[co];
    }
    __syncthreads();

    // channel-sum: wave 0, lane = co; 5 butterfly reductions over 64 lanes
    if (wv == 0) {
        float vy[5];
        #pragma unroll
        for (int wjl = 0; wjl < 5; ++wjl) vy[wjl] = Y[lane * 5 + wjl];
        #pragma unroll
        for (int wjl = 0; wjl < 5; ++wjl) {
            float v = vy[wjl];
            #pragma unroll
            for (int off = 32; off > 0; off >>= 1)
                v += __shfl_down(v, off, 64);
            if (lane == 0)
                out[((n * 5 + dj) * 10 + hj) * 10 + whalf * 5 + wjl] = v;
        }
    }
}

extern "C" void kernel_launch(void* const* d_in, const int* in_sizes, int n_in,
                              void* d_out, int out_size, void* d_ws, size_t ws_size,
                              hipStream_t stream) {
    const float* x    = (const float*)d_in[0];
    const float* w    = (const float*)d_in[1];
    const float* bias = (const float*)d_in[2];
    float*       out  = (float*)d_out;
    unsigned short* wt = (unsigned short*)d_ws;                        // 512000 B
    unsigned short* xp = (unsigned short*)((char*)d_ws + 512512);      // 18,382,848 B
    const size_t XP_NEED = 512512 + 18382848;
    const int do_x = (ws_size >= XP_NEED) ? 1 : 0;

    prep<<<dim3(2088), 256, 0, stream>>>(x, w, xp, wt, do_x);
    if (do_x)
        fused_main<true ><<<dim3(1600), 256, 0, stream>>>(x, xp, wt, bias, out);
    else
        fused_main<false><<<dim3(1600), 256, 0, stream>>>(x, xp, wt, bias, out);
}